// Round 2
// baseline (130.080 us; speedup 1.0000x reference)
//
#include <hip/hip_runtime.h>
#include <math.h>

// Round-robin tournament pairs for parallel Jacobi on 8 indices (p<q).
static __device__ const int RRp[7][4] = {
  {0,1,2,3},{0,5,1,2},{0,4,3,1},{0,3,2,1},{0,2,1,6},{0,1,4,5},{0,2,3,4}
};
static __device__ const int RRq[7][4] = {
  {7,6,5,4},{6,7,4,3},{5,6,7,2},{4,5,6,7},{3,4,5,7},{2,3,7,6},{1,7,6,5}
};

__device__ __forceinline__ double rdin(const void* p, int idx, bool isdbl) {
  return isdbl ? ((const double*)p)[idx] : (double)((const float*)p)[idx];
}

__device__ __forceinline__ bool detect_dbl(const void* xv) {
  // f64 data reinterpreted as f32 words shows wild exponents in the low words;
  // true f32 N(0,1) never exceeds 1e6. Scan 64 words (>= 32 doubles).
  const float* xq = (const float*)xv;
  bool isdbl = false;
  for (int j = 0; j < 64; ++j) {
    float a = fabsf(xq[j]);
    if (!(a < 1e6f)) isdbl = true;
  }
  return isdbl;
}

// ---------------------------------------------------------------------------
// Phase 1: one wave (64 threads) per sample. Builds H, Jacobi-eigendecomposes,
// computes Jacobian g[8][64] and h = g/P, emits I_b[i] = M = g^T h (fp32).
// Single-wave block => every __syncthreads is a near-free single-wave barrier.
// ---------------------------------------------------------------------------
__global__ __launch_bounds__(64) void fi_phase1(
    const void* __restrict__ xv,
    const void* __restrict__ kv,
    const void* __restrict__ bv,
    float* __restrict__ out, int Bn)
{
  const int i = blockIdx.x;
  const int t = threadIdx.x;           // 0..63

  __shared__ double pw[64];
  __shared__ double Hre[8][8], Him[8][8];
  __shared__ double Vre[8][8], Vim[8][8];
  __shared__ double Fre[8][8], Fim[8][8];
  __shared__ double Gre[8][8], Gim[8][8];
  __shared__ double ampre[8], ampim[8], invPs[8], ev[8];
  __shared__ float gk[64][8], hk[64][8];   // k-major Jacobian columns (fp32)

  const bool isdbl = detect_dbl(xv);

  // ---- pw = x @ K + bias (fp64) -------------------------------------------
  {
    double acc = rdin(bv, t, isdbl);
    #pragma unroll
    for (int j = 0; j < 4; ++j)
      acc += rdin(xv, i*4 + j, isdbl) * rdin(kv, j*64 + t, isdbl);
    pw[t] = acc;
  }
  __syncthreads();

  // ---- build H = sum_k pw_k P_k (analytic Pauli strings), init V = I ------
  {
    int r = t >> 3, c = t & 7;
    int m = r ^ c;
    double hre = 0.0, him = 0.0;
    for (int u = 0; u < 8; ++u) {
      int k = 0;
      double pr = 1.0, pim = 0.0;
      #pragma unroll
      for (int q = 0; q < 3; ++q) {
        int bit = 2 - q;
        int f  = (m >> bit) & 1;
        int ch = (u >> bit) & 1;
        int rb = (r >> bit) & 1;
        int d  = f ? (ch ? 2 : 1) : (ch ? 3 : 0);  // I=0,X=1,Y=2,Z=3
        k = (k << 2) | d;
        if (d == 2) {
          double nr = rb ? -pim : pim;
          double ni = rb ?  pr  : -pr;
          pr = nr; pim = ni;
        } else if (d == 3 && rb) { pr = -pr; pim = -pim; }
      }
      double w = pw[k];
      hre += w * pr; him += w * pim;
    }
    Hre[r][c] = hre; Him[r][c] = him;
    Vre[r][c] = (r == c) ? 1.0 : 0.0;
    Vim[r][c] = 0.0;
  }
  __syncthreads();

  // ---- complex Hermitian Jacobi, fp32 rotation params, fp64 updates -------
  for (int sweep = 0; sweep < 6; ++sweep) {
    for (int round = 0; round < 7; ++round) {
      int tl = t & 31;
      int pp = tl >> 3, j = tl & 7;
      int p = RRp[round][pp], q = RRq[round][pp];
      double dcc = 1.0, dsg = 0.0, dwr = 1.0, dwi = 0.0;
      {
        double a = Hre[p][p], b = Hre[q][q];
        double zr = Hre[p][q], zi = Him[p][q];
        double r2d = zr*zr + zi*zi;
        if (r2d > 1e-30) {
          float rr = sqrtf((float)r2d);
          float wr = (float)zr / rr, wi = (float)zi / rr;
          float th = (float)(b - a) / (2.0f * rr);
          float tt = ((th >= 0.0f) ? 1.0f : -1.0f) / (fabsf(th) + sqrtf(1.0f + th*th));
          float cc = 1.0f / sqrtf(1.0f + tt*tt);
          float sg = tt * cc;
          dcc = (double)cc; dsg = (double)sg;
          dwr = (double)wr; dwi = (double)wi;
        }
      }
      __syncthreads();
      if (t < 32) {                      // H column update: A <- A*U
        double upr = Hre[j][p], upi = Him[j][p];
        double uqr = Hre[j][q], uqi = Him[j][q];
        Hre[j][p] = dcc*upr - dsg*(dwr*uqr + dwi*uqi);
        Him[j][p] = dcc*upi - dsg*(dwr*uqi - dwi*uqr);
        Hre[j][q] = dsg*(dwr*upr - dwi*upi) + dcc*uqr;
        Him[j][q] = dsg*(dwr*upi + dwi*upr) + dcc*uqi;
      } else {                           // V column update: V <- V*U
        double vpr = Vre[j][p], vpi = Vim[j][p];
        double vqr = Vre[j][q], vqi = Vim[j][q];
        Vre[j][p] = dcc*vpr - dsg*(dwr*vqr + dwi*vqi);
        Vim[j][p] = dcc*vpi - dsg*(dwr*vqi - dwi*vqr);
        Vre[j][q] = dsg*(dwr*vpr - dwi*vpi) + dcc*vqr;
        Vim[j][q] = dsg*(dwr*vpi + dwi*vpr) + dcc*vqi;
      }
      __syncthreads();
      if (t < 32) {                      // H row update: A <- U^H * A
        double rpr = Hre[p][j], rpi = Him[p][j];
        double rqr = Hre[q][j], rqi = Him[q][j];
        Hre[p][j] = dcc*rpr - dsg*(dwr*rqr - dwi*rqi);
        Him[p][j] = dcc*rpi - dsg*(dwr*rqi + dwi*rqr);
        Hre[q][j] = dsg*(dwr*rpr + dwi*rpi) + dcc*rqr;
        Him[q][j] = dsg*(dwr*rpi - dwi*rpr) + dcc*rqi;
      }
      __syncthreads();
    }
  }

  if (t < 8) ev[t] = Hre[t][t];
  __syncthreads();

  // ---- F (Daleckii-Krein) + amp + 1/P -------------------------------------
  {
    int s = t >> 3, u = t & 7;
    double dm = 0.5 * (ev[s] - ev[u]);
    double av = 0.5 * (ev[s] + ev[u]);
    double sc = (fabs(dm) < 1e-6) ? (1.0 - dm*dm*(1.0/6.0)) : (sin(dm)/dm);
    Fre[s][u] =  cos(av) * sc;
    Fim[s][u] = -sin(av) * sc;
  }
  if (t < 8) {
    double are = 0.0, aim = 0.0;
    #pragma unroll
    for (int s = 0; s < 8; ++s) {
      double ce = cos(ev[s]), se = -sin(ev[s]);
      double c0r = Vre[0][s], c0i = -Vim[0][s];
      double wr2 = c0r*ce - c0i*se;
      double wi2 = c0r*se + c0i*ce;
      double vjr = Vre[t][s], vji = Vim[t][s];
      are += vjr*wr2 - vji*wi2;
      aim += vjr*wi2 + vji*wr2;
    }
    ampre[t] = are; ampim[t] = aim;
    double P = are*are + aim*aim;
    invPs[t] = 1.0 / fmax(P, 1e-300);
  }
  __syncthreads();

  // ---- G[s][rho] = sum_t V[rho][t] F[s][t] conj(V[0][t]) ------------------
  {
    int s = t >> 3, rho = t & 7;
    double gr = 0.0, gi = 0.0;
    #pragma unroll
    for (int u = 0; u < 8; ++u) {
      double c0r = Vre[0][u], c0i = -Vim[0][u];
      double fr = Fre[s][u], fi = Fim[s][u];
      double fcr = fr*c0r - fi*c0i;
      double fci = fr*c0i + fi*c0r;
      double vr = Vre[rho][u], vi = Vim[rho][u];
      gr += vr*fcr - vi*fci;
      gi += vr*fci + vi*fcr;
    }
    Gre[s][rho] = gr; Gim[s][rho] = gi;
  }
  __syncthreads();

  // ---- Jacobian column k = t: g[:,k], h[:,k] ------------------------------
  {
    const int k = t;
    const int d0 = (k >> 4) & 3, d1 = (k >> 2) & 3, d2 = k & 3;
    const int m = ((((d0 == 1) | (d0 == 2)) ? 1 : 0) << 2)
                | ((((d1 == 1) | (d1 == 2)) ? 1 : 0) << 1)
                |  (((d2 == 1) | (d2 == 2)) ? 1 : 0);
    double yre[8], yim[8];
    #pragma unroll
    for (int s = 0; s < 8; ++s) { yre[s] = 0.0; yim[s] = 0.0; }
    for (int r = 0; r < 8; ++r) {
      double pr = 1.0, pim = 0.0;
      const int dd0[3] = {d0, d1, d2};
      #pragma unroll
      for (int q = 0; q < 3; ++q) {
        int rb = (r >> (2 - q)) & 1;
        int d = dd0[q];
        if (d == 2) {
          double nr = rb ? -pim : pim;
          double ni = rb ?  pr  : -pr;
          pr = nr; pim = ni;
        } else if (d == 3 && rb) { pr = -pr; pim = -pim; }
      }
      int rm = r ^ m;
      #pragma unroll
      for (int s = 0; s < 8; ++s) {
        double vr = Vre[r][s], vi = -Vim[r][s];
        double gr2 = Gre[s][rm], gi2 = Gim[s][rm];
        double ar = pr*gr2 - pim*gi2;
        double ai = pr*gi2 + pim*gr2;
        yre[s] += vr*ar - vi*ai;
        yim[s] += vr*ai + vi*ar;
      }
    }
    #pragma unroll
    for (int p = 0; p < 8; ++p) {
      double dr = 0.0, di = 0.0;
      #pragma unroll
      for (int s = 0; s < 8; ++s) {
        double ysr =  yim[s], ysi = -yre[s];   // * (-i)
        double vr = Vre[p][s], vi = Vim[p][s];
        dr += vr*ysr - vi*ysi;
        di += vr*ysi + vi*ysr;
      }
      double gg = 2.0 * (ampre[p]*dr + ampim[p]*di);
      gk[k][p] = (float)gg;
      hk[k][p] = (float)(gg * invPs[p]);
    }
  }
  __syncthreads();

  // ---- I_b[i] = M = g^T h, fp32, stored straight to global ----------------
  {
    float hv[8];
    #pragma unroll
    for (int p = 0; p < 8; ++p) hv[p] = hk[t][p];
    float* ob = out + (size_t)Bn * 65536 + (size_t)i * 4096;
    for (int k = 0; k < 64; ++k) {
      const float4 ga = *(const float4*)&gk[k][0];   // broadcast reads
      const float4 gb = *(const float4*)&gk[k][4];
      float acc = ga.x*hv[0] + ga.y*hv[1] + ga.z*hv[2] + ga.w*hv[3]
                + gb.x*hv[4] + gb.y*hv[5] + gb.z*hv[6] + gb.w*hv[7];
      ob[k*64 + t] = acc;                            // coalesced 256B/wave
    }
  }
}

// ---------------------------------------------------------------------------
// Phase 2: 16 blocks per sample, 256 threads. Reads M from the I_b output
// region (written by phase 1, L2-hot) and streams I_k = x_j*x_l*M[k,m].
// ---------------------------------------------------------------------------
__global__ __launch_bounds__(256) void fi_phase2(
    const void* __restrict__ xv,
    float* __restrict__ out, int Bn)
{
  const int bx = blockIdx.x;
  const int i  = bx >> 4;
  const int blk = bx & 15;              // j = blk>>2, kbase = (blk&3)*16
  const int t = threadIdx.x;

  __shared__ __align__(16) float Ms[16][68];

  const bool isdbl = detect_dbl(xv);

  const int rg = t >> 4;                // 0..15
  const int q4 = (t & 15) << 2;         // 0,4,..,60

  const float* Mg = out + (size_t)Bn * 65536 + (size_t)i * 4096;
  *(float4*)&Ms[rg][q4] =
      *(const float4*)(Mg + (size_t)(((blk & 3) << 4) + rg) * 64 + q4);

  const int j = blk >> 2;
  float xjf = (float)rdin(xv, i*4 + j, isdbl);
  float xx[4];
  #pragma unroll
  for (int l = 0; l < 4; ++l)
    xx[l] = xjf * (float)rdin(xv, i*4 + l, isdbl);

  __syncthreads();

  float* ok = out + (size_t)i * 65536 + (size_t)blk * 4096;
  #pragma unroll
  for (int it = 0; it < 4; ++it) {
    int local = it*16 + rg;             // row within this block's 64 rows
    int kk = local >> 2;                // 0..15
    int l  = local & 3;
    const float4 mv = *(const float4*)&Ms[kk][q4];
    float s = xx[l];
    *(float4*)(ok + (size_t)local * 64 + q4) =
        make_float4(s*mv.x, s*mv.y, s*mv.z, s*mv.w);
  }
}

extern "C" void kernel_launch(void* const* d_in, const int* in_sizes, int n_in,
                              void* d_out, int out_size, void* d_ws, size_t ws_size,
                              hipStream_t stream) {
  (void)n_in; (void)d_ws; (void)ws_size; (void)out_size;
  int Bn = in_sizes[0] / 4;   // 256
  fi_phase1<<<Bn, 64, 0, stream>>>(d_in[0], d_in[1], d_in[2], (float*)d_out, Bn);
  fi_phase2<<<Bn * 16, 256, 0, stream>>>(d_in[0], (float*)d_out, Bn);
}

// Round 3
// 119.078 us; speedup vs baseline: 1.0924x; 1.0924x over previous
//
#include <hip/hip_runtime.h>
#include <math.h>

// Round-robin tournament pairs for parallel Jacobi on 8 indices (p<q).
static __device__ const int RRp[7][4] = {
  {0,1,2,3},{0,5,1,2},{0,4,3,1},{0,3,2,1},{0,2,1,6},{0,1,4,5},{0,2,3,4}
};
static __device__ const int RRq[7][4] = {
  {7,6,5,4},{6,7,4,3},{5,6,7,2},{4,5,6,7},{3,4,5,7},{2,3,7,6},{1,7,6,5}
};

__device__ __forceinline__ double rdin(const void* p, int idx, bool isdbl) {
  return isdbl ? ((const double*)p)[idx] : (double)((const float*)p)[idx];
}

__device__ __forceinline__ bool detect_dbl(const void* xv) {
  // f64 data reinterpreted as f32 words shows wild exponents in the low
  // (mantissa) words; true f32 N(0,1) never exceeds 1e6. 64 words => P(miss)~2e-8.
  const float* xq = (const float*)xv;
  bool isdbl = false;
  for (int j = 0; j < 64; ++j) {
    float a = fabsf(xq[j]);
    if (!(a < 1e6f)) isdbl = true;
  }
  return isdbl;
}

// ---------------------------------------------------------------------------
// Phase 1: one wave (64 threads) per sample, all-fp32 internal math.
// Builds H, Jacobi-eigendecomposes (5 sweeps), computes Jacobian g[8][64],
// h = g/P, emits I_b[i] = M = g^T h (fp32). Single-wave block => barriers
// are compiler-elided to waitcnt only.
// ---------------------------------------------------------------------------
__global__ __launch_bounds__(64) void fi_phase1(
    const void* __restrict__ xv,
    const void* __restrict__ kv,
    const void* __restrict__ bv,
    float* __restrict__ out, int Bn)
{
  const int i = blockIdx.x;
  const int t = threadIdx.x;           // 0..63

  __shared__ float pw[64];
  __shared__ float Hre[8][8], Him[8][8];
  __shared__ float Vre[8][8], Vim[8][8];
  __shared__ float Fre[8][8], Fim[8][8];
  __shared__ float Gre[8][8], Gim[8][8];
  __shared__ float ampre[8], ampim[8], invPs[8], ev[8];
  __shared__ __align__(16) float gk[64][8], hk[64][8];  // k-major Jacobian cols

  const bool isdbl = detect_dbl(xv);

  // ---- pw = x @ K + bias ---------------------------------------------------
  {
    float acc = (float)rdin(bv, t, isdbl);
    #pragma unroll
    for (int j = 0; j < 4; ++j)
      acc += (float)rdin(xv, i*4 + j, isdbl) * (float)rdin(kv, j*64 + t, isdbl);
    pw[t] = acc;
  }
  __syncthreads();

  // ---- build H = sum_k pw_k P_k (analytic Pauli strings), init V = I ------
  {
    int r = t >> 3, c = t & 7;
    int m = r ^ c;
    float hre = 0.0f, him = 0.0f;
    for (int u = 0; u < 8; ++u) {
      int k = 0;
      float pr = 1.0f, pim = 0.0f;
      #pragma unroll
      for (int q = 0; q < 3; ++q) {
        int bit = 2 - q;
        int f  = (m >> bit) & 1;
        int ch = (u >> bit) & 1;
        int rb = (r >> bit) & 1;
        int d  = f ? (ch ? 2 : 1) : (ch ? 3 : 0);  // I=0,X=1,Y=2,Z=3
        k = (k << 2) | d;
        if (d == 2) {
          float nr = rb ? -pim : pim;
          float ni = rb ?  pr  : -pr;
          pr = nr; pim = ni;
        } else if (d == 3 && rb) { pr = -pr; pim = -pim; }
      }
      float w = pw[k];
      hre += w * pr; him += w * pim;
    }
    Hre[r][c] = hre; Him[r][c] = him;
    Vre[r][c] = (r == c) ? 1.0f : 0.0f;
    Vim[r][c] = 0.0f;
  }
  __syncthreads();

  // ---- complex Hermitian Jacobi, fp32, parallel round-robin ---------------
  for (int sweep = 0; sweep < 5; ++sweep) {
    for (int round = 0; round < 7; ++round) {
      const int tl = t & 31;
      const int pp = tl >> 3, j = tl & 7;
      const int p = RRp[round][pp], q = RRq[round][pp];
      // prefetch params + own column elements before any write
      float cc = 1.0f, sg = 0.0f, wr = 1.0f, wi = 0.0f;
      {
        float a = Hre[p][p], b = Hre[q][q];
        float zr = Hre[p][q], zi = Him[p][q];
        float r2 = zr*zr + zi*zi;
        if (r2 > 1e-24f) {
          float rr = sqrtf(r2);
          wr = zr / rr; wi = zi / rr;
          float th = (b - a) / (2.0f * rr);
          float tt = ((th >= 0.0f) ? 1.0f : -1.0f) / (fabsf(th) + sqrtf(1.0f + th*th));
          cc = 1.0f / sqrtf(1.0f + tt*tt);
          sg = tt * cc;
        }
      }
      float e0r, e0i, e1r, e1i;
      if (t < 32) { e0r = Hre[j][p]; e0i = Him[j][p]; e1r = Hre[j][q]; e1i = Him[j][q]; }
      else        { e0r = Vre[j][p]; e0i = Vim[j][p]; e1r = Vre[j][q]; e1i = Vim[j][q]; }
      __syncthreads();
      if (t < 32) {                      // H column update: A <- A*U
        Hre[j][p] = cc*e0r - sg*(wr*e1r + wi*e1i);
        Him[j][p] = cc*e0i - sg*(wr*e1i - wi*e1r);
        Hre[j][q] = sg*(wr*e0r - wi*e0i) + cc*e1r;
        Him[j][q] = sg*(wr*e0i + wi*e0r) + cc*e1i;
      } else {                           // V column update: V <- V*U
        Vre[j][p] = cc*e0r - sg*(wr*e1r + wi*e1i);
        Vim[j][p] = cc*e0i - sg*(wr*e1i - wi*e1r);
        Vre[j][q] = sg*(wr*e0r - wi*e0i) + cc*e1r;
        Vim[j][q] = sg*(wr*e0i + wi*e0r) + cc*e1i;
      }
      __syncthreads();
      if (t < 32) {                      // H row update: A <- U^H * A
        float rpr = Hre[p][j], rpi = Him[p][j];
        float rqr = Hre[q][j], rqi = Him[q][j];
        Hre[p][j] = cc*rpr - sg*(wr*rqr - wi*rqi);
        Him[p][j] = cc*rpi - sg*(wr*rqi + wi*rqr);
        Hre[q][j] = sg*(wr*rpr + wi*rpi) + cc*rqr;
        Him[q][j] = sg*(wr*rpi - wi*rpr) + cc*rqi;
      }
      __syncthreads();
    }
  }

  if (t < 8) ev[t] = Hre[t][t];
  __syncthreads();

  // ---- F (Daleckii-Krein) + amp + 1/P -------------------------------------
  {
    int s = t >> 3, u = t & 7;
    float dm = 0.5f * (ev[s] - ev[u]);
    float av = 0.5f * (ev[s] + ev[u]);
    float sc = (fabsf(dm) < 1e-3f) ? (1.0f - dm*dm*(1.0f/6.0f)) : (sinf(dm)/dm);
    Fre[s][u] =  cosf(av) * sc;
    Fim[s][u] = -sinf(av) * sc;
  }
  if (t < 8) {
    float are = 0.0f, aim = 0.0f;
    #pragma unroll
    for (int s = 0; s < 8; ++s) {
      float ce = cosf(ev[s]), se = -sinf(ev[s]);
      float c0r = Vre[0][s], c0i = -Vim[0][s];
      float wr2 = c0r*ce - c0i*se;
      float wi2 = c0r*se + c0i*ce;
      float vjr = Vre[t][s], vji = Vim[t][s];
      are += vjr*wr2 - vji*wi2;
      aim += vjr*wi2 + vji*wr2;
    }
    ampre[t] = are; ampim[t] = aim;
    float P = are*are + aim*aim;
    invPs[t] = 1.0f / fmaxf(P, 1e-30f);
  }
  __syncthreads();

  // ---- G[s][rho] = sum_u V[rho][u] F[s][u] conj(V[0][u]) ------------------
  {
    int s = t >> 3, rho = t & 7;
    float gr = 0.0f, gi = 0.0f;
    #pragma unroll
    for (int u = 0; u < 8; ++u) {
      float c0r = Vre[0][u], c0i = -Vim[0][u];
      float fr = Fre[s][u], fi = Fim[s][u];
      float fcr = fr*c0r - fi*c0i;
      float fci = fr*c0i + fi*c0r;
      float vr = Vre[rho][u], vi = Vim[rho][u];
      gr += vr*fcr - vi*fci;
      gi += vr*fci + vi*fcr;
    }
    Gre[s][rho] = gr; Gim[s][rho] = gi;
  }
  __syncthreads();

  // ---- Jacobian column k = t: g[:,k], h[:,k] ------------------------------
  {
    const int k = t;
    const int d0 = (k >> 4) & 3, d1 = (k >> 2) & 3, d2 = k & 3;
    const int m = ((((d0 == 1) | (d0 == 2)) ? 1 : 0) << 2)
                | ((((d1 == 1) | (d1 == 2)) ? 1 : 0) << 1)
                |  (((d2 == 1) | (d2 == 2)) ? 1 : 0);
    float yre[8], yim[8];
    #pragma unroll
    for (int s = 0; s < 8; ++s) { yre[s] = 0.0f; yim[s] = 0.0f; }
    for (int r = 0; r < 8; ++r) {
      float pr = 1.0f, pim = 0.0f;       // ph_k(r), in {±1, ±i}
      const int dd0[3] = {d0, d1, d2};
      #pragma unroll
      for (int q = 0; q < 3; ++q) {
        int rb = (r >> (2 - q)) & 1;
        int d = dd0[q];
        if (d == 2) {
          float nr = rb ? -pim : pim;
          float ni = rb ?  pr  : -pr;
          pr = nr; pim = ni;
        } else if (d == 3 && rb) { pr = -pr; pim = -pim; }
      }
      int rm = r ^ m;
      #pragma unroll
      for (int s = 0; s < 8; ++s) {      // y_s += conj(V[r][s]) ph G[s][r^m]
        float vr = Vre[r][s], vi = -Vim[r][s];
        float gr2 = Gre[s][rm], gi2 = Gim[s][rm];
        float ar = pr*gr2 - pim*gi2;
        float ai = pr*gi2 + pim*gr2;
        yre[s] += vr*ar - vi*ai;
        yim[s] += vr*ai + vi*ar;
      }
    }
    #pragma unroll
    for (int p = 0; p < 8; ++p) {        // damp_p = sum_s V[p][s] * (-i*y_s)
      float dr = 0.0f, di = 0.0f;
      #pragma unroll
      for (int s = 0; s < 8; ++s) {
        float ysr =  yim[s], ysi = -yre[s];   // * (-i)
        float vr = Vre[p][s], vi = Vim[p][s];
        dr += vr*ysr - vi*ysi;
        di += vr*ysi + vi*ysr;
      }
      float gg = 2.0f * (ampre[p]*dr + ampim[p]*di);
      gk[k][p] = gg;
      hk[k][p] = gg * invPs[p];
    }
  }
  __syncthreads();

  // ---- I_b[i] = M = g^T h, stored straight to global ----------------------
  {
    float hv[8];
    #pragma unroll
    for (int p = 0; p < 8; ++p) hv[p] = hk[t][p];
    float* ob = out + (size_t)Bn * 65536 + (size_t)i * 4096;
    for (int k = 0; k < 64; ++k) {
      const float4 ga = *(const float4*)&gk[k][0];   // broadcast reads
      const float4 gb = *(const float4*)&gk[k][4];
      float acc = ga.x*hv[0] + ga.y*hv[1] + ga.z*hv[2] + ga.w*hv[3]
                + gb.x*hv[4] + gb.y*hv[5] + gb.z*hv[6] + gb.w*hv[7];
      ob[k*64 + t] = acc;                            // coalesced 256B/wave
    }
  }
}

// ---------------------------------------------------------------------------
// Phase 2: 16 blocks per sample, 256 threads. Reads M from the I_b output
// region (written by phase 1, L2-hot) and streams I_k = x_j*x_l*M[k,m].
// ---------------------------------------------------------------------------
__global__ __launch_bounds__(256) void fi_phase2(
    const void* __restrict__ xv,
    float* __restrict__ out, int Bn)
{
  const int bx = blockIdx.x;
  const int i  = bx >> 4;
  const int blk = bx & 15;              // j = blk>>2, kbase = (blk&3)*16
  const int t = threadIdx.x;

  __shared__ __align__(16) float Ms[16][68];

  const bool isdbl = detect_dbl(xv);

  const int rg = t >> 4;                // 0..15
  const int q4 = (t & 15) << 2;         // 0,4,..,60

  const float* Mg = out + (size_t)Bn * 65536 + (size_t)i * 4096;
  *(float4*)&Ms[rg][q4] =
      *(const float4*)(Mg + (size_t)(((blk & 3) << 4) + rg) * 64 + q4);

  const int j = blk >> 2;
  float xjf = (float)rdin(xv, i*4 + j, isdbl);
  float xx[4];
  #pragma unroll
  for (int l = 0; l < 4; ++l)
    xx[l] = xjf * (float)rdin(xv, i*4 + l, isdbl);

  __syncthreads();

  float* ok = out + (size_t)i * 65536 + (size_t)blk * 4096;
  #pragma unroll
  for (int it = 0; it < 4; ++it) {
    int local = it*16 + rg;             // row within this block's 64 rows
    int kk = local >> 2;                // 0..15
    int l  = local & 3;
    const float4 mv = *(const float4*)&Ms[kk][q4];
    float s = xx[l];
    *(float4*)(ok + (size_t)local * 64 + q4) =
        make_float4(s*mv.x, s*mv.y, s*mv.z, s*mv.w);
  }
}

extern "C" void kernel_launch(void* const* d_in, const int* in_sizes, int n_in,
                              void* d_out, int out_size, void* d_ws, size_t ws_size,
                              hipStream_t stream) {
  (void)n_in; (void)d_ws; (void)ws_size; (void)out_size;
  int Bn = in_sizes[0] / 4;   // 256
  fi_phase1<<<Bn, 64, 0, stream>>>(d_in[0], d_in[1], d_in[2], (float*)d_out, Bn);
  fi_phase2<<<Bn * 16, 256, 0, stream>>>(d_in[0], (float*)d_out, Bn);
}

// Round 4
// 111.761 us; speedup vs baseline: 1.1639x; 1.0655x over previous
//
#include <hip/hip_runtime.h>
#include <math.h>

__device__ __forceinline__ double rdin(const void* p, int idx, bool isdbl) {
  return isdbl ? ((const double*)p)[idx] : (double)((const float*)p)[idx];
}

__device__ __forceinline__ bool detect_dbl(const void* xv) {
  // f64 data reinterpreted as f32 words shows wild exponents in the low
  // (mantissa) words; true f32 N(0,1) never exceeds 1e6. 64 words => P(miss)~2e-8.
  const float* xq = (const float*)xv;
  bool isdbl = false;
  for (int j = 0; j < 64; ++j) {
    float a = fabsf(xq[j]);
    if (!(a < 1e6f)) isdbl = true;
  }
  return isdbl;
}

// ---------------------------------------------------------------------------
// Phase 1: one wave (64 threads) per sample, all-fp32 internal math.
// Builds H, Jacobi-eigendecomposes (4 sweeps, closed-form round-robin pairs,
// fully unrolled, zero memory loads in the loop), computes Jacobian column
// g[:,t] in registers, h = g/P to LDS, emits I_b[i] row t = M[t,:] = g_t . h
// with dwordx4 stores. Single-wave block => barriers are waitcnt-only.
// ---------------------------------------------------------------------------
__global__ __launch_bounds__(64) void fi_phase1(
    const void* __restrict__ xv,
    const void* __restrict__ kv,
    const void* __restrict__ bv,
    float* __restrict__ out, int Bn)
{
  const int i = blockIdx.x;
  const int t = threadIdx.x;           // 0..63

  __shared__ float pw[64];
  __shared__ float Hre[8][8], Him[8][8];
  __shared__ float Vre[8][8], Vim[8][8];
  __shared__ float Fre[8][8], Fim[8][8];
  __shared__ float Gre[8][8], Gim[8][8];
  __shared__ float ampre[8], ampim[8], invPs[8], ev[8];
  __shared__ __align__(16) float hk[64][8];   // h columns, k-major

  const bool isdbl = detect_dbl(xv);

  // ---- pw = x @ K + bias ---------------------------------------------------
  {
    float acc = (float)rdin(bv, t, isdbl);
    #pragma unroll
    for (int j = 0; j < 4; ++j)
      acc += (float)rdin(xv, i*4 + j, isdbl) * (float)rdin(kv, j*64 + t, isdbl);
    pw[t] = acc;
  }
  __syncthreads();

  // ---- build H = sum_k pw_k P_k (analytic Pauli strings), init V = I ------
  {
    int r = t >> 3, c = t & 7;
    int m = r ^ c;
    float hre = 0.0f, him = 0.0f;
    for (int u = 0; u < 8; ++u) {
      int k = 0;
      float pr = 1.0f, pim = 0.0f;
      #pragma unroll
      for (int q = 0; q < 3; ++q) {
        int bit = 2 - q;
        int f  = (m >> bit) & 1;
        int ch = (u >> bit) & 1;
        int rb = (r >> bit) & 1;
        int d  = f ? (ch ? 2 : 1) : (ch ? 3 : 0);  // I=0,X=1,Y=2,Z=3
        k = (k << 2) | d;
        if (d == 2) {
          float nr = rb ? -pim : pim;
          float ni = rb ?  pr  : -pr;
          pr = nr; pim = ni;
        } else if (d == 3 && rb) { pr = -pr; pim = -pim; }
      }
      float w = pw[k];
      hre += w * pr; him += w * pim;
    }
    Hre[r][c] = hre; Him[r][c] = him;
    Vre[r][c] = (r == c) ? 1.0f : 0.0f;
    Vim[r][c] = 0.0f;
  }
  __syncthreads();

  // ---- complex Hermitian Jacobi, fp32, closed-form round-robin pairs ------
  const int tl = t & 31;
  const int pp = tl >> 3, j = tl & 7;
  #pragma unroll
  for (int sweep = 0; sweep < 4; ++sweep) {
    #pragma unroll
    for (int round = 0; round < 7; ++round) {
      // circle-method tournament: fix 7, rotate 0..6.  All-ALU, no loads.
      int p, q;
      if (pp == 0) { p = 7; q = round; }
      else {
        p = round + pp;     if (p >= 7) p -= 7;
        q = round + 7 - pp; if (q >= 7) q -= 7;
      }
      // rotation params + own column elements, one LDS wait
      float cc = 1.0f, sg = 0.0f, wr = 1.0f, wi = 0.0f;
      {
        float a = Hre[p][p], b = Hre[q][q];
        float zr = Hre[p][q], zi = Him[p][q];
        float r2 = zr*zr + zi*zi;
        if (r2 > 1e-24f) {
          float rr = sqrtf(r2);
          wr = zr / rr; wi = zi / rr;
          float th = (b - a) / (2.0f * rr);
          float tt = ((th >= 0.0f) ? 1.0f : -1.0f) / (fabsf(th) + sqrtf(1.0f + th*th));
          cc = 1.0f / sqrtf(1.0f + tt*tt);
          sg = tt * cc;
        }
      }
      float e0r, e0i, e1r, e1i;
      if (t < 32) { e0r = Hre[j][p]; e0i = Him[j][p]; e1r = Hre[j][q]; e1i = Him[j][q]; }
      else        { e0r = Vre[j][p]; e0i = Vim[j][p]; e1r = Vre[j][q]; e1i = Vim[j][q]; }
      __syncthreads();
      if (t < 32) {                      // H column update: A <- A*U
        Hre[j][p] = cc*e0r - sg*(wr*e1r + wi*e1i);
        Him[j][p] = cc*e0i - sg*(wr*e1i - wi*e1r);
        Hre[j][q] = sg*(wr*e0r - wi*e0i) + cc*e1r;
        Him[j][q] = sg*(wr*e0i + wi*e0r) + cc*e1i;
      } else {                           // V column update: V <- V*U
        Vre[j][p] = cc*e0r - sg*(wr*e1r + wi*e1i);
        Vim[j][p] = cc*e0i - sg*(wr*e1i - wi*e1r);
        Vre[j][q] = sg*(wr*e0r - wi*e0i) + cc*e1r;
        Vim[j][q] = sg*(wr*e0i + wi*e0r) + cc*e1i;
      }
      __syncthreads();
      if (t < 32) {                      // H row update: A <- U^H * A
        float rpr = Hre[p][j], rpi = Him[p][j];
        float rqr = Hre[q][j], rqi = Him[q][j];
        Hre[p][j] = cc*rpr - sg*(wr*rqr - wi*rqi);
        Him[p][j] = cc*rpi - sg*(wr*rqi + wi*rqr);
        Hre[q][j] = sg*(wr*rpr + wi*rpi) + cc*rqr;
        Him[q][j] = sg*(wr*rpi - wi*rpr) + cc*rqi;
      }
      __syncthreads();
    }
  }

  if (t < 8) ev[t] = Hre[t][t];
  __syncthreads();

  // ---- F (Daleckii-Krein) + amp + 1/P -------------------------------------
  {
    int s = t >> 3, u = t & 7;
    float dm = 0.5f * (ev[s] - ev[u]);
    float av = 0.5f * (ev[s] + ev[u]);
    float sc = (fabsf(dm) < 1e-3f) ? (1.0f - dm*dm*(1.0f/6.0f)) : (__sinf(dm)/dm);
    Fre[s][u] =  __cosf(av) * sc;
    Fim[s][u] = -__sinf(av) * sc;
  }
  if (t < 8) {
    float are = 0.0f, aim = 0.0f;
    #pragma unroll
    for (int s = 0; s < 8; ++s) {
      float ce = __cosf(ev[s]), se = -__sinf(ev[s]);
      float c0r = Vre[0][s], c0i = -Vim[0][s];
      float wr2 = c0r*ce - c0i*se;
      float wi2 = c0r*se + c0i*ce;
      float vjr = Vre[t][s], vji = Vim[t][s];
      are += vjr*wr2 - vji*wi2;
      aim += vjr*wi2 + vji*wr2;
    }
    ampre[t] = are; ampim[t] = aim;
    float P = are*are + aim*aim;
    invPs[t] = 1.0f / fmaxf(P, 1e-30f);
  }
  __syncthreads();

  // ---- G[s][rho] = sum_u V[rho][u] F[s][u] conj(V[0][u]) ------------------
  {
    int s = t >> 3, rho = t & 7;
    float gr = 0.0f, gi = 0.0f;
    #pragma unroll
    for (int u = 0; u < 8; ++u) {
      float c0r = Vre[0][u], c0i = -Vim[0][u];
      float fr = Fre[s][u], fi = Fim[s][u];
      float fcr = fr*c0r - fi*c0i;
      float fci = fr*c0i + fi*c0r;
      float vr = Vre[rho][u], vi = Vim[rho][u];
      gr += vr*fcr - vi*fci;
      gi += vr*fci + vi*fcr;
    }
    Gre[s][rho] = gr; Gim[s][rho] = gi;
  }
  __syncthreads();

  // ---- Jacobian column k = t: gcol[p] in registers, h to LDS --------------
  float gcol[8];
  {
    const int k = t;
    const int d0 = (k >> 4) & 3, d1 = (k >> 2) & 3, d2 = k & 3;
    const int m = ((((d0 == 1) | (d0 == 2)) ? 1 : 0) << 2)
                | ((((d1 == 1) | (d1 == 2)) ? 1 : 0) << 1)
                |  (((d2 == 1) | (d2 == 2)) ? 1 : 0);
    float yre[8], yim[8];
    #pragma unroll
    for (int s = 0; s < 8; ++s) { yre[s] = 0.0f; yim[s] = 0.0f; }
    #pragma unroll
    for (int r = 0; r < 8; ++r) {
      float pr = 1.0f, pim = 0.0f;       // ph_k(r), in {±1, ±i}
      const int dd0[3] = {d0, d1, d2};
      #pragma unroll
      for (int q = 0; q < 3; ++q) {
        int rb = (r >> (2 - q)) & 1;
        int d = dd0[q];
        if (d == 2) {
          float nr = rb ? -pim : pim;
          float ni = rb ?  pr  : -pr;
          pr = nr; pim = ni;
        } else if (d == 3 && rb) { pr = -pr; pim = -pim; }
      }
      int rm = r ^ m;
      #pragma unroll
      for (int s = 0; s < 8; ++s) {      // y_s += conj(V[r][s]) ph G[s][r^m]
        float vr = Vre[r][s], vi = -Vim[r][s];
        float gr2 = Gre[s][rm], gi2 = Gim[s][rm];
        float ar = pr*gr2 - pim*gi2;
        float ai = pr*gi2 + pim*gr2;
        yre[s] += vr*ar - vi*ai;
        yim[s] += vr*ai + vi*ar;
      }
    }
    #pragma unroll
    for (int p = 0; p < 8; ++p) {        // damp_p = sum_s V[p][s] * (-i*y_s)
      float dr = 0.0f, di = 0.0f;
      #pragma unroll
      for (int s = 0; s < 8; ++s) {
        float ysr =  yim[s], ysi = -yre[s];   // * (-i)
        float vr = Vre[p][s], vi = Vim[p][s];
        dr += vr*ysr - vi*ysi;
        di += vr*ysi + vi*ysr;
      }
      float gg = 2.0f * (ampre[p]*dr + ampim[p]*di);
      gcol[p] = gg;
      hk[k][p] = gg * invPs[p];
    }
  }
  __syncthreads();

  // ---- I_b row t: M[t][m] = sum_p gcol[p]*h[p][m], dwordx4 stores ---------
  {
    float* ob = out + (size_t)Bn * 65536 + (size_t)i * 4096 + (size_t)t * 64;
    #pragma unroll
    for (int m4 = 0; m4 < 16; ++m4) {
      float4 vv;
      #pragma unroll
      for (int l = 0; l < 4; ++l) {
        int m = m4*4 + l;
        const float4 ha = *(const float4*)&hk[m][0];   // broadcast reads
        const float4 hb = *(const float4*)&hk[m][4];
        float acc = gcol[0]*ha.x + gcol[1]*ha.y + gcol[2]*ha.z + gcol[3]*ha.w
                  + gcol[4]*hb.x + gcol[5]*hb.y + gcol[6]*hb.z + gcol[7]*hb.w;
        (&vv.x)[l] = acc;
      }
      *(float4*)(ob + m4*4) = vv;
    }
  }
}

// ---------------------------------------------------------------------------
// Phase 2: 16 blocks per sample, 256 threads. Reads M from the I_b output
// region (written by phase 1, L2/L3-hot) and streams I_k = x_j*x_l*M[k,m].
// ---------------------------------------------------------------------------
__global__ __launch_bounds__(256) void fi_phase2(
    const void* __restrict__ xv,
    float* __restrict__ out, int Bn)
{
  const int bx = blockIdx.x;
  const int i  = bx >> 4;
  const int blk = bx & 15;              // j = blk>>2, kbase = (blk&3)*16
  const int t = threadIdx.x;

  __shared__ __align__(16) float Ms[16][68];

  const bool isdbl = detect_dbl(xv);

  const int rg = t >> 4;                // 0..15
  const int q4 = (t & 15) << 2;         // 0,4,..,60

  const float* Mg = out + (size_t)Bn * 65536 + (size_t)i * 4096;
  *(float4*)&Ms[rg][q4] =
      *(const float4*)(Mg + (size_t)(((blk & 3) << 4) + rg) * 64 + q4);

  const int j = blk >> 2;
  float xjf = (float)rdin(xv, i*4 + j, isdbl);
  float xx[4];
  #pragma unroll
  for (int l = 0; l < 4; ++l)
    xx[l] = xjf * (float)rdin(xv, i*4 + l, isdbl);

  __syncthreads();

  float* ok = out + (size_t)i * 65536 + (size_t)blk * 4096;
  #pragma unroll
  for (int it = 0; it < 4; ++it) {
    int local = it*16 + rg;             // row within this block's 64 rows
    int kk = local >> 2;                // 0..15
    int l  = local & 3;
    const float4 mv = *(const float4*)&Ms[kk][q4];
    float s = xx[l];
    *(float4*)(ok + (size_t)local * 64 + q4) =
        make_float4(s*mv.x, s*mv.y, s*mv.z, s*mv.w);
  }
}

extern "C" void kernel_launch(void* const* d_in, const int* in_sizes, int n_in,
                              void* d_out, int out_size, void* d_ws, size_t ws_size,
                              hipStream_t stream) {
  (void)n_in; (void)d_ws; (void)ws_size; (void)out_size;
  int Bn = in_sizes[0] / 4;   // 256
  fi_phase1<<<Bn, 64, 0, stream>>>(d_in[0], d_in[1], d_in[2], (float*)d_out, Bn);
  fi_phase2<<<Bn * 16, 256, 0, stream>>>(d_in[0], (float*)d_out, Bn);
}